// Round 1
// baseline (677.433 us; speedup 1.0000x reference)
//
#include <hip/hip_runtime.h>

#define N_NODES 100000
#define N_EDGES 1600000
#define SLOPE_ 0.2f

// ---------------- CSR build ----------------

__global__ void hist_k(const int* __restrict__ row, int* __restrict__ cnt) {
    int e = blockIdx.x * 256 + threadIdx.x;           // grid sized exactly E/256
    atomicAdd(&cnt[row[e]], 1);
}

// per-block inclusive scan over 512 elements (256 threads x 2)
__global__ void scanA_k(const int* __restrict__ cnt, int n,
                        int* __restrict__ incl, int* __restrict__ bsum) {
    __shared__ int s[256];
    int t = threadIdx.x;
    int base = blockIdx.x * 512;
    int i0 = base + 2 * t, i1 = i0 + 1;
    int a = (i0 < n) ? cnt[i0] : 0;
    int b = (i1 < n) ? cnt[i1] : 0;
    int p = a + b;
    s[t] = p;
    __syncthreads();
    for (int off = 1; off < 256; off <<= 1) {
        int v = (t >= off) ? s[t - off] : 0;
        __syncthreads();
        s[t] += v;
        __syncthreads();
    }
    int excl = s[t] - p;
    if (i0 < n) incl[i0] = excl + a;
    if (i1 < n) incl[i1] = excl + a + b;
    if (t == 255) bsum[blockIdx.x] = s[255];
}

// exclusive scan of block sums (single block, nb <= 256)
__global__ void scanB_k(const int* __restrict__ bsum, int nb, int* __restrict__ boff) {
    __shared__ int s[256];
    int t = threadIdx.x;
    int v = (t < nb) ? bsum[t] : 0;
    s[t] = v;
    __syncthreads();
    for (int off = 1; off < 256; off <<= 1) {
        int u = (t >= off) ? s[t - off] : 0;
        __syncthreads();
        s[t] += u;
        __syncthreads();
    }
    if (t < nb) boff[t] = s[t] - v;
}

// row_ptr[i+1] = global inclusive; cursor[i] = global exclusive
__global__ void scanC_k(const int* __restrict__ incl, const int* __restrict__ boff,
                        const int* __restrict__ cnt, int n,
                        int* __restrict__ row_ptr, int* __restrict__ cursor) {
    int i = blockIdx.x * 256 + threadIdx.x;
    if (i < n) {
        int g = incl[i] + boff[i >> 9];
        row_ptr[i + 1] = g;
        cursor[i] = g - cnt[i];
        if (i == 0) row_ptr[0] = 0;
    }
}

__global__ void scatter_k(const int* __restrict__ row, const int* __restrict__ col,
                          const float* __restrict__ ew, int* __restrict__ cursor,
                          int* __restrict__ col_s, float* __restrict__ w_s) {
    int e = blockIdx.x * 256 + threadIdx.x;           // grid sized exactly E/256
    int r = row[e];
    int p = atomicAdd(&cursor[r], 1);
    col_s[p] = col[e];
    w_s[p] = ew[e];
}

// ---------------- dense GEMM: out[N][COLS] = A[N][K] @ W[K][COLS] ----------------
// tile: 32 rows x COLS cols, K-chunks of 64. 256 threads.

template <int K, int COLS>
__global__ void gemm_nt(const float* __restrict__ A, const float* __restrict__ W,
                        float* __restrict__ out) {
    constexpr int TK = 64;
    constexpr int CG = COLS / 4;       // threads along cols (each owns 4 cols)
    constexpr int RG = 256 / CG;       // thread groups along rows
    constexpr int RPT = 32 / RG;       // rows per thread
    __shared__ float xs[32][TK + 4];   // +4 pad: bank spread, keeps 16B alignment
    __shared__ float ws[TK][COLS];
    int t = threadIdx.x;
    int row0 = blockIdx.x * 32;
    int tx = t % CG, ty = t / CG;
    float acc[RPT][4];
#pragma unroll
    for (int r = 0; r < RPT; r++)
        for (int c = 0; c < 4; c++) acc[r][c] = 0.f;

    for (int k0 = 0; k0 < K; k0 += TK) {
        // stage A tile: 32 x TK
        for (int l = t; l < 32 * (TK / 4); l += 256) {
            int r = l / (TK / 4), c4 = l % (TK / 4);
            float4 v = *(const float4*)(A + (size_t)(row0 + r) * K + k0 + 4 * c4);
            *(float4*)(&xs[r][4 * c4]) = v;
        }
        // stage W chunk: TK x COLS
        for (int l = t; l < TK * (COLS / 4); l += 256) {
            int r = l / (COLS / 4), c4 = l % (COLS / 4);
            float4 v = *(const float4*)(W + (size_t)(k0 + r) * COLS + 4 * c4);
            *(float4*)(&ws[r][4 * c4]) = v;
        }
        __syncthreads();
#pragma unroll 8
        for (int k = 0; k < TK; k++) {
            float4 wv = *(const float4*)(&ws[k][4 * tx]);
#pragma unroll
            for (int r = 0; r < RPT; r++) {
                float xv = xs[ty * RPT + r][k];
                acc[r][0] += xv * wv.x;
                acc[r][1] += xv * wv.y;
                acc[r][2] += xv * wv.z;
                acc[r][3] += xv * wv.w;
            }
        }
        __syncthreads();
    }
#pragma unroll
    for (int r = 0; r < RPT; r++) {
        float4 v = make_float4(acc[r][0], acc[r][1], acc[r][2], acc[r][3]);
        *(float4*)(out + (size_t)(row0 + ty * RPT + r) * COLS + 4 * tx) = v;
    }
}

// ---------------- pull-SpMM with fused bias + leaky-relu (+ dropout) ----------------
// one wave per output row

template <int D, bool DROP>
__global__ void spmm_ep(const int* __restrict__ row_ptr, const int* __restrict__ cols,
                        const float* __restrict__ w, const float* __restrict__ h,
                        const float* __restrict__ bias, const float* __restrict__ mask,
                        float* __restrict__ out, int n) {
    int wid = (int)((blockIdx.x * (size_t)blockDim.x + threadIdx.x) >> 6);
    int lane = threadIdx.x & 63;
    if (wid >= n) return;
    int s = row_ptr[wid], e = row_ptr[wid + 1];
    if (D == 128) {
        float ax = 0.f, ay = 0.f;
        for (int i = s; i < e; i++) {
            int c = cols[i];
            float wt = w[i];
            float2 v = *(const float2*)(h + (size_t)c * 128 + 2 * lane);
            ax += wt * v.x;
            ay += wt * v.y;
        }
        float2 b = *(const float2*)(bias + 2 * lane);
        float ox = ax + b.x, oy = ay + b.y;
        ox = ox > 0.f ? ox : SLOPE_ * ox;
        oy = oy > 0.f ? oy : SLOPE_ * oy;
        if (DROP) {
            float2 m = *(const float2*)(mask + (size_t)wid * 128 + 2 * lane);
            ox *= m.x;
            oy *= m.y;
        }
        float2 o = make_float2(ox, oy);
        *(float2*)(out + (size_t)wid * 128 + 2 * lane) = o;
    } else {  // D == 64
        float a = 0.f;
        for (int i = s; i < e; i++) {
            int c = cols[i];
            float wt = w[i];
            a += wt * h[(size_t)c * 64 + lane];
        }
        float o = a + bias[lane];
        o = o > 0.f ? o : SLOPE_ * o;
        out[(size_t)wid * 64 + lane] = o;
    }
}

// ---------------- fused classifier: out = lrelu(h@W3+b3)@W4 + b4 ----------------

__global__ void clf_k(const float* __restrict__ h, const float* __restrict__ W3,
                      const float* __restrict__ b3, const float* __restrict__ W4,
                      const float* __restrict__ b4, float* __restrict__ out) {
    __shared__ float W3s[64][32];
    __shared__ float W4s[32][16];
    __shared__ float b3s[32], b4s[16];
    __shared__ float hs[32][64];
    __shared__ float t4[32][33];  // pad
    int t = threadIdx.x;
    for (int l = t; l < 64 * 32; l += 256) W3s[l / 32][l % 32] = W3[l];
    for (int l = t; l < 32 * 16; l += 256) W4s[l / 16][l % 16] = W4[l];
    if (t < 32) b3s[t] = b3[t];
    if (t < 16) b4s[t] = b4[t];
    int row0 = blockIdx.x * 32;
    for (int l = t; l < 512; l += 256) {
        int r = l / 16, c4 = l % 16;
        *(float4*)(&hs[r][4 * c4]) = *(const float4*)(h + (size_t)(row0 + r) * 64 + 4 * c4);
    }
    __syncthreads();
    for (int l = t; l < 1024; l += 256) {
        int r = l / 32, c = l % 32;
        float a = b3s[c];
#pragma unroll 8
        for (int k = 0; k < 64; k++) a += hs[r][k] * W3s[k][c];
        t4[r][c] = a > 0.f ? a : SLOPE_ * a;
    }
    __syncthreads();
    for (int l = t; l < 512; l += 256) {
        int r = l / 16, c = l % 16;
        float a = b4s[c];
#pragma unroll
        for (int k = 0; k < 32; k++) a += t4[r][k] * W4s[k][c];
        out[(size_t)(row0 + r) * 16 + c] = a;
    }
}

// ---------------- launch ----------------

extern "C" void kernel_launch(void* const* d_in, const int* in_sizes, int n_in,
                              void* d_out, int out_size, void* d_ws, size_t ws_size,
                              hipStream_t stream) {
    const float* x = (const float*)d_in[0];
    const int* row = (const int*)d_in[1];
    const int* col = (const int*)d_in[2];
    const float* ew = (const float*)d_in[3];
    const float* W1 = (const float*)d_in[4];
    const float* b1 = (const float*)d_in[5];
    const float* W2 = (const float*)d_in[6];
    const float* b2 = (const float*)d_in[7];
    const float* W3 = (const float*)d_in[8];
    const float* b3 = (const float*)d_in[9];
    const float* W4 = (const float*)d_in[10];
    const float* b4 = (const float*)d_in[11];
    const float* mask = (const float*)d_in[12];
    float* out = (float*)d_out;

    const int N = N_NODES, E = N_EDGES;

    float* h0 = (float*)d_ws;                 // N*128
    float* h1 = h0 + (size_t)N * 128;         // N*128
    int* cnt = (int*)(h1 + (size_t)N * 128);  // N
    int* incl = cnt + N;                      // N
    int* row_ptr = incl + N;                  // N+1
    int* cursor = row_ptr + N + 1;            // N
    int* bsum = cursor + N;                   // 256
    int* boff = bsum + 256;                   // 256
    int* col_s = boff + 256;                  // E
    float* w_s = (float*)(col_s + E);         // E

    int nbScan = (N + 511) / 512;

    hipMemsetAsync(cnt, 0, (size_t)N * sizeof(int), stream);
    hist_k<<<E / 256, 256, 0, stream>>>(row, cnt);
    scanA_k<<<nbScan, 256, 0, stream>>>(cnt, N, incl, bsum);
    scanB_k<<<1, 256, 0, stream>>>(bsum, nbScan, boff);
    scanC_k<<<(N + 255) / 256, 256, 0, stream>>>(incl, boff, cnt, N, row_ptr, cursor);
    scatter_k<<<E / 256, 256, 0, stream>>>(row, col, ew, cursor, col_s, w_s);

    gemm_nt<256, 128><<<N / 32, 256, 0, stream>>>(x, W1, h0);
    spmm_ep<128, true><<<(N + 3) / 4, 256, 0, stream>>>(row_ptr, col_s, w_s, h0, b1, mask, h1, N);
    gemm_nt<128, 64><<<N / 32, 256, 0, stream>>>(h1, W2, h0);  // h2 aliases h0
    spmm_ep<64, false><<<(N + 3) / 4, 256, 0, stream>>>(row_ptr, col_s, w_s, h0, b2, nullptr, h1, N);
    clf_k<<<N / 32, 256, 0, stream>>>(h1, W3, b3, W4, b4, out);
}

// Round 2
// 513.493 us; speedup vs baseline: 1.3193x; 1.3193x over previous
//
#include <hip/hip_runtime.h>
#include <hip/hip_bf16.h>

#define N_NODES 100000
#define N_EDGES 1600000
#define SLOPE_ 0.2f

typedef __attribute__((ext_vector_type(8))) short bf16x8;
typedef __attribute__((ext_vector_type(4))) float f32x4;

__device__ __forceinline__ short f2bf(float f) {
    __hip_bfloat16 h = __float2bfloat16(f);
    return *reinterpret_cast<short*>(&h);
}
__device__ __forceinline__ float bflo(unsigned u) { return __uint_as_float(u << 16); }
__device__ __forceinline__ float bfhi(unsigned u) { return __uint_as_float(u & 0xFFFF0000u); }
__device__ __forceinline__ float bf2f(short s) {
    return __uint_as_float(((unsigned)(unsigned short)s) << 16);
}

// ---------------- CSR build ----------------

__global__ void hist_k(const int* __restrict__ row, int* __restrict__ cnt) {
    int e = blockIdx.x * 256 + threadIdx.x;  // grid sized exactly E/256
    atomicAdd(&cnt[row[e]], 1);
}

__global__ void scanA_k(const int* __restrict__ cnt, int n,
                        int* __restrict__ incl, int* __restrict__ bsum) {
    __shared__ int s[256];
    int t = threadIdx.x;
    int base = blockIdx.x * 512;
    int i0 = base + 2 * t, i1 = i0 + 1;
    int a = (i0 < n) ? cnt[i0] : 0;
    int b = (i1 < n) ? cnt[i1] : 0;
    int p = a + b;
    s[t] = p;
    __syncthreads();
    for (int off = 1; off < 256; off <<= 1) {
        int v = (t >= off) ? s[t - off] : 0;
        __syncthreads();
        s[t] += v;
        __syncthreads();
    }
    int excl = s[t] - p;
    if (i0 < n) incl[i0] = excl + a;
    if (i1 < n) incl[i1] = excl + a + b;
    if (t == 255) bsum[blockIdx.x] = s[255];
}

__global__ void scanB_k(const int* __restrict__ bsum, int nb, int* __restrict__ boff) {
    __shared__ int s[256];
    int t = threadIdx.x;
    int v = (t < nb) ? bsum[t] : 0;
    s[t] = v;
    __syncthreads();
    for (int off = 1; off < 256; off <<= 1) {
        int u = (t >= off) ? s[t - off] : 0;
        __syncthreads();
        s[t] += u;
        __syncthreads();
    }
    if (t < nb) boff[t] = s[t] - v;
}

__global__ void scanC_k(const int* __restrict__ incl, const int* __restrict__ boff,
                        const int* __restrict__ cnt, int n,
                        int* __restrict__ row_ptr, int* __restrict__ cursor) {
    int i = blockIdx.x * 256 + threadIdx.x;
    if (i < n) {
        int g = incl[i] + boff[i >> 9];
        row_ptr[i + 1] = g;
        cursor[i] = g - cnt[i];
        if (i == 0) row_ptr[0] = 0;
    }
}

__global__ void scatter_k(const int* __restrict__ row, const int* __restrict__ col,
                          const float* __restrict__ ew, int* __restrict__ cursor,
                          int* __restrict__ col_s, float* __restrict__ w_s) {
    int e = blockIdx.x * 256 + threadIdx.x;  // grid sized exactly E/256
    int r = row[e];
    int p = atomicAdd(&cursor[r], 1);
    col_s[p] = col[e];
    w_s[p] = ew[e];
}

// ---------------- weight prep: Wt[n][k] = bf16(W[k][n]) ----------------

__global__ void prep_k(const float* __restrict__ W1, const float* __restrict__ W2,
                       short* __restrict__ Wt1, short* __restrict__ Wt2) {
    int i = blockIdx.x * 256 + threadIdx.x;
    if (i < 128 * 256) {
        int n = i >> 8, k = i & 255;
        Wt1[i] = f2bf(W1[k * 128 + n]);
    }
    int j = i - 128 * 256;
    if (j >= 0 && j < 64 * 128) {
        int n = j >> 7, k = j & 127;
        Wt2[j] = f2bf(W2[k * 64 + n]);
    }
}

// ---------------- MFMA GEMM: out[M][COLS](bf16) = A[M][K] @ W[K][COLS] ----------------
// Block = 4 waves; wave w owns rows row0+16w..+15, all COLS cols.
// B-fragments read directly from global Wt[n][k] (bf16, k-contiguous, L2-resident).
// mfma_f32_16x16x32_bf16: A-frag lane l: row=l%16, k=(l/16)*8+e
//                         B-frag lane l: col=l%16, k=(l/16)*8+e
//                         D     lane l: col=l%16, row=(l/16)*4+r   [verified layout]

template <int K, int COLS, bool ABF16>
__global__ void gemm_mfma(const void* __restrict__ Ap, const short* __restrict__ Wt,
                          short* __restrict__ out, int M) {
    constexpr int NT = COLS / 16;
    int l = threadIdx.x & 63;
    int wv = threadIdx.x >> 6;
    int row0 = blockIdx.x * 64 + wv * 16;
    int ln = l & 15, g = l >> 4;
    int arow = row0 + ln;
    bool rowok = arow < M;
    f32x4 acc[NT];
#pragma unroll
    for (int t = 0; t < NT; t++) acc[t] = (f32x4){0.f, 0.f, 0.f, 0.f};

    for (int k0 = 0; k0 < K; k0 += 32) {
        int kk = k0 + g * 8;
        bf16x8 af = {};
        if constexpr (ABF16) {
            if (rowok) af = *(const bf16x8*)((const short*)Ap + (size_t)arow * K + kk);
        } else {
            if (rowok) {
                const float* ap = (const float*)Ap + (size_t)arow * K + kk;
                float4 u0 = *(const float4*)ap;
                float4 u1 = *(const float4*)(ap + 4);
                af[0] = f2bf(u0.x); af[1] = f2bf(u0.y);
                af[2] = f2bf(u0.z); af[3] = f2bf(u0.w);
                af[4] = f2bf(u1.x); af[5] = f2bf(u1.y);
                af[6] = f2bf(u1.z); af[7] = f2bf(u1.w);
            }
        }
#pragma unroll
        for (int nt = 0; nt < NT; nt++) {
            bf16x8 bfr = *(const bf16x8*)(Wt + (size_t)(nt * 16 + ln) * K + kk);
            acc[nt] = __builtin_amdgcn_mfma_f32_16x16x32_bf16(af, bfr, acc[nt], 0, 0, 0);
        }
    }
#pragma unroll
    for (int nt = 0; nt < NT; nt++) {
#pragma unroll
        for (int r = 0; r < 4; r++) {
            int orow = row0 + g * 4 + r;
            if (orow < M) out[(size_t)orow * COLS + nt * 16 + ln] = f2bf(acc[nt][r]);
        }
    }
}

// ---------------- pull-SpMM (bf16 gather, fp32 accum) + bias + lrelu (+drop) ----------------

template <int D, bool DROP>
__global__ void spmm_bf(const int* __restrict__ row_ptr, const int* __restrict__ cols,
                        const float* __restrict__ w, const short* __restrict__ h,
                        const float* __restrict__ bias, const float* __restrict__ mask,
                        short* __restrict__ out, int n) {
    int wid = (int)((blockIdx.x * (size_t)blockDim.x + threadIdx.x) >> 6);
    int lane = threadIdx.x & 63;
    if (wid >= n) return;
    int s = row_ptr[wid], e = row_ptr[wid + 1];
    if (D == 128) {
        float ax = 0.f, ay = 0.f;
        int i = s;
        for (; i + 2 <= e; i += 2) {
            int c0 = cols[i], c1 = cols[i + 1];
            float w0 = w[i], w1 = w[i + 1];
            unsigned u0 = *(const unsigned*)(h + (size_t)c0 * 128 + 2 * lane);
            unsigned u1 = *(const unsigned*)(h + (size_t)c1 * 128 + 2 * lane);
            ax += w0 * bflo(u0); ay += w0 * bfhi(u0);
            ax += w1 * bflo(u1); ay += w1 * bfhi(u1);
        }
        if (i < e) {
            int c0 = cols[i];
            float w0 = w[i];
            unsigned u0 = *(const unsigned*)(h + (size_t)c0 * 128 + 2 * lane);
            ax += w0 * bflo(u0); ay += w0 * bfhi(u0);
        }
        float2 b = *(const float2*)(bias + 2 * lane);
        float ox = ax + b.x, oy = ay + b.y;
        ox = ox > 0.f ? ox : SLOPE_ * ox;
        oy = oy > 0.f ? oy : SLOPE_ * oy;
        if (DROP) {
            float2 m = *(const float2*)(mask + (size_t)wid * 128 + 2 * lane);
            ox *= m.x;
            oy *= m.y;
        }
        unsigned ov = (unsigned)(unsigned short)f2bf(ox) |
                      ((unsigned)(unsigned short)f2bf(oy) << 16);
        *(unsigned*)(out + (size_t)wid * 128 + 2 * lane) = ov;
    } else {  // D == 64
        float a = 0.f;
        int i = s;
        for (; i + 2 <= e; i += 2) {
            int c0 = cols[i], c1 = cols[i + 1];
            float w0 = w[i], w1 = w[i + 1];
            float v0 = bf2f(h[(size_t)c0 * 64 + lane]);
            float v1 = bf2f(h[(size_t)c1 * 64 + lane]);
            a += w0 * v0;
            a += w1 * v1;
        }
        if (i < e) {
            a += w[i] * bf2f(h[(size_t)cols[i] * 64 + lane]);
        }
        float o = a + bias[lane];
        o = o > 0.f ? o : SLOPE_ * o;
        out[(size_t)wid * 64 + lane] = f2bf(o);
    }
}

// ---------------- fused classifier: out = lrelu(h@W3+b3)@W4 + b4 (h bf16) ----------------

__global__ void clf_k(const short* __restrict__ h, const float* __restrict__ W3,
                      const float* __restrict__ b3, const float* __restrict__ W4,
                      const float* __restrict__ b4, float* __restrict__ out) {
    __shared__ float W3s[64][32];
    __shared__ float W4s[32][16];
    __shared__ float b3s[32], b4s[16];
    __shared__ float hs[32][64];
    __shared__ float t4[32][33];  // pad
    int t = threadIdx.x;
    for (int l = t; l < 64 * 32; l += 256) W3s[l / 32][l % 32] = W3[l];
    for (int l = t; l < 32 * 16; l += 256) W4s[l / 16][l % 16] = W4[l];
    if (t < 32) b3s[t] = b3[t];
    if (t < 16) b4s[t] = b4[t];
    int row0 = blockIdx.x * 32;
    {
        bf16x8 v = *(const bf16x8*)(h + (size_t)row0 * 64 + t * 8);
        int r = t >> 3, c0 = (t & 7) << 3;
#pragma unroll
        for (int j = 0; j < 8; j++) hs[r][c0 + j] = bf2f(v[j]);
    }
    __syncthreads();
    for (int l = t; l < 1024; l += 256) {
        int r = l / 32, c = l % 32;
        float a = b3s[c];
#pragma unroll 8
        for (int k = 0; k < 64; k++) a += hs[r][k] * W3s[k][c];
        t4[r][c] = a > 0.f ? a : SLOPE_ * a;
    }
    __syncthreads();
    for (int l = t; l < 512; l += 256) {
        int r = l / 16, c = l % 16;
        float a = b4s[c];
#pragma unroll
        for (int k = 0; k < 32; k++) a += t4[r][k] * W4s[k][c];
        out[(size_t)(row0 + r) * 16 + c] = a;
    }
}

// ---------------- launch ----------------

extern "C" void kernel_launch(void* const* d_in, const int* in_sizes, int n_in,
                              void* d_out, int out_size, void* d_ws, size_t ws_size,
                              hipStream_t stream) {
    const float* x = (const float*)d_in[0];
    const int* row = (const int*)d_in[1];
    const int* col = (const int*)d_in[2];
    const float* ew = (const float*)d_in[3];
    const float* W1 = (const float*)d_in[4];
    const float* b1 = (const float*)d_in[5];
    const float* W2 = (const float*)d_in[6];
    const float* b2 = (const float*)d_in[7];
    const float* W3 = (const float*)d_in[8];
    const float* b3 = (const float*)d_in[9];
    const float* W4 = (const float*)d_in[10];
    const float* b4 = (const float*)d_in[11];
    const float* mask = (const float*)d_in[12];
    float* out = (float*)d_out;

    const int N = N_NODES, E = N_EDGES;

    short* h0 = (short*)d_ws;            // N*128 bf16 (gemm1 out)
    short* h1 = h0 + (size_t)N * 128;    // N*128 bf16 (spmm1 out)
    short* h2 = h1 + (size_t)N * 128;    // N*64  bf16 (gemm2 out)
    short* h3 = h2 + (size_t)N * 64;     // N*64  bf16 (spmm2 out)
    short* Wt1 = h3 + (size_t)N * 64;    // 128*256 bf16
    short* Wt2 = Wt1 + 128 * 256;        // 64*128 bf16
    int* cnt = (int*)(Wt2 + 64 * 128);   // N
    int* incl = cnt + N;                 // N
    int* row_ptr = incl + N;             // N+1
    int* cursor = row_ptr + N + 1;       // N
    int* bsum = cursor + N;              // 256
    int* boff = bsum + 256;              // 256
    int* col_s = boff + 256;             // E
    float* w_s = (float*)(col_s + E);    // E

    int nbScan = (N + 511) / 512;

    hipMemsetAsync(cnt, 0, (size_t)N * sizeof(int), stream);
    hist_k<<<E / 256, 256, 0, stream>>>(row, cnt);
    scanA_k<<<nbScan, 256, 0, stream>>>(cnt, N, incl, bsum);
    scanB_k<<<1, 256, 0, stream>>>(bsum, nbScan, boff);
    scanC_k<<<(N + 255) / 256, 256, 0, stream>>>(incl, boff, cnt, N, row_ptr, cursor);
    scatter_k<<<E / 256, 256, 0, stream>>>(row, col, ew, cursor, col_s, w_s);
    prep_k<<<160, 256, 0, stream>>>(W1, W2, Wt1, Wt2);

    gemm_mfma<256, 128, false><<<(N + 63) / 64, 256, 0, stream>>>(x, Wt1, h0, N);
    spmm_bf<128, true><<<(N + 3) / 4, 256, 0, stream>>>(row_ptr, col_s, w_s, h0, b1, mask, h1, N);
    gemm_mfma<128, 64, true><<<(N + 63) / 64, 256, 0, stream>>>(h1, Wt2, h2, N);
    spmm_bf<64, false><<<(N + 3) / 4, 256, 0, stream>>>(row_ptr, col_s, w_s, h2, b2, nullptr, h3, N);
    clf_k<<<N / 32, 256, 0, stream>>>(h3, W3, b3, W4, b4, out);
}